// Round 3
// baseline (69.939 us; speedup 1.0000x reference)
//
#include <hip/hip_runtime.h>
#include <hip/hip_bf16.h>
#include <stdint.h>

typedef __attribute__((ext_vector_type(4))) float f32x4;
typedef __attribute__((ext_vector_type(8))) short bf16x8;

#define NCH  128
#define NREL 8

__device__ __forceinline__ unsigned short f2bf(float f) {
    unsigned u = __builtin_bit_cast(unsigned, f);
    u += 0x7fffu + ((u >> 16) & 1u);          // RNE to bf16
    return (unsigned short)(u >> 16);
}

__device__ __forceinline__ bool mask_used(const unsigned char* um, int stride, int s) {
    if (stride == 1) return um[s] != 0;
    if (stride == 4) return ((const int*)um)[s] != 0;
    return ((const long long*)um)[s] != 0;
}

// ---------------------------------------------------------------------------
// K1 (fused prep + hist):
//  blocks [0, histBlocks): 32 nodes each -- copy cached history rows to out,
//    ballot-compact non-cached ids into glist (one global atomic per block).
//  blocks [histBlocks, histBlocks+16): convert W fp32 -> bf16 Wb in the
//    B-fragment layout Wb[((kt*128+col)<<5)+kk] = bf16(W[kt*32+kk][col]).
//    prep block 0 additionally detects used_mask element width -> cn[1].
//  cn[0] is zeroed by hipMemsetAsync before this kernel.
// ---------------------------------------------------------------------------
__global__ __launch_bounds__(256)
void k_hist_prep(const float* __restrict__ hb, const int* __restrict__ hm,
                 const int* __restrict__ hs, const float* __restrict__ W,
                 unsigned short* __restrict__ Wb, float* __restrict__ out,
                 int* __restrict__ cn, int* __restrict__ glist,
                 const unsigned char* __restrict__ um_raw,
                 int num_node, int histBlocks) {
    const int t = threadIdx.x;

    if ((int)blockIdx.x >= histBlocks) {                 // ---- prep role ----
        const int pb = blockIdx.x - histBlocks;
        int o = pb * 256 + t;
        #pragma unroll 8
        for (int i = 0; i < 32; ++i, o += 4096) {
            const int kk = o & 31;
            const int h  = (o >> 5) & (NCH - 1);
            const int kt = o >> 12;
            Wb[o] = f2bf(W[(kt * 32 + kk) * NCH + h]);
        }
        if (pb == 0) {
            __shared__ unsigned sA, sB;
            if (t == 0) { sA = 0; sB = 0; }
            __syncthreads();
            unsigned a = 0, b = 0;
            #pragma unroll 4
            for (int p = t; p < 1024; p += 256) {
                const unsigned v = um_raw[p];
                if ((p & 3) != 0) a |= v;   // bool stored 1B -> data off 4-align
                if ((p & 7) == 4) b |= v;   // int32 -> data at 4 mod 8
            }
            if (a) atomicOr(&sA, 1u);
            if (b) atomicOr(&sB, 1u);
            __syncthreads();
            if (t == 0) cn[1] = sA ? 1 : (sB ? 4 : 8);
        }
        return;
    }

    // ---- hist role: 32 nodes ----
    __shared__ int cList[32], ncList[32];
    __shared__ int nNC, nC, gbase;
    const int n = blockIdx.x * 32 + t;
    if (t < 64) {                                        // wave 0 classifies
        const bool valid  = (t < 32) && (n < num_node);
        const bool cached = valid && (hs[0] > 0) && (hm[n] != -1);
        const bool nc     = valid && !cached;
        const unsigned long long mC  = __ballot(cached);
        const unsigned long long mNC = __ballot(nc);
        const unsigned long long below = (t == 63) ? ~0ull >> 1 : ((1ull << t) - 1);
        if (cached) cList[__popcll(mC & below)]  = n;
        if (nc)     ncList[__popcll(mNC & below)] = n;
        if (t == 0) { nC = __popcll(mC); nNC = __popcll(mNC); }
    }
    __syncthreads();
    // half-wave (32 lanes) per cached row; candidates hw, hw+8, hw+16, hw+24
    const int hw = t >> 5, l = t & 31;
    const int myNC = nNC, myC = nC;
    int   node[4];
    f32x4 v[4];
    #pragma unroll 4
    for (int j = 0; j < 4; ++j) {
        const int i = hw + j * 8;
        node[j] = (i < myC) ? cList[i] : -1;
        if (node[j] >= 0)
            v[j] = *(const f32x4*)(hb + (long)node[j] * NCH + l * 4);
    }
    #pragma unroll 4
    for (int j = 0; j < 4; ++j) {
        if (node[j] >= 0)
            *(f32x4*)(out + (long)node[j] * NCH + l * 4) = v[j];
    }
    if (t == 0) gbase = atomicAdd(&cn[0], myNC);
    __syncthreads();
    if (t < myNC) glist[gbase + t] = ncList[t];
}

// ---------------------------------------------------------------------------
// K2: 16 non-cached nodes per 256-thread block.
//   phase 1: half-wave per node (2 reps); per rep ALL 16 edge gathers are
//            issued before any consumption (single latency chain per rep),
//            8-way predicated accumulate -> bf16 swizzled LDS A[16][1024]
//   phase 2: out[16x128] = A[16x1024] * Wb[1024x128] via mfma 16x16x32 bf16
// ---------------------------------------------------------------------------
__global__ __launch_bounds__(256, 3)
void k_main(const float* __restrict__ x, const unsigned short* __restrict__ Wb,
            const int* __restrict__ ptr, const int* __restrict__ idx,
            const int* __restrict__ et, const unsigned char* __restrict__ um,
            const int* __restrict__ cn, const int* __restrict__ glist,
            float* __restrict__ out) {
    __shared__ __align__(16) char As[16 * NREL * NCH * 2];   // 32 KB, XOR-swizzled
    __shared__ int   nid[16];
    __shared__ float invdeg[16];

    const int cnt  = cn[0];
    const int base = blockIdx.x * 16;
    if (base >= cnt) return;
    const int mstride = cn[1];
    const int t = threadIdx.x;
    if (t < 16) {
        const int e = base + t;
        nid[t]    = (e < cnt) ? glist[e] : -1;
        invdeg[t] = 0.0f;
    }
    __syncthreads();

    const int hw = t >> 5;          // half-wave id 0..7
    const int l  = t & 31;          // lane in half-wave; owns channels 4l..4l+3
    const int lbase = t & 32;       // wave-lane base of this half-wave

    for (int rep = 0; rep < 2; ++rep) {
        const int nd = hw + rep * 8;
        const int n  = nid[nd];
        float acc[NREL][4];
        #pragma unroll
        for (int r = 0; r < NREL; ++r)
            #pragma unroll
            for (int j = 0; j < 4; ++j) acc[r][j] = 0.0f;
        if (n >= 0) {
            const int p0 = ptr[n], p1 = ptr[n + 1];
            const int deg = p1 - p0;
            if (l == 0) invdeg[nd] = (deg > 0) ? 1.0f / (float)deg : 0.0f;
            // lanes 0..15 fetch edge metadata; pack (rel<<24)|src -> 1 shfl/edge
            int myPk = NREL << 24;      // default: src 0, dead relation
            if (l < 16 && (p0 + l) < p1) {
                const int e = p0 + l;
                const int s = idx[e];
                const int tt = et[e];
                const int r = (mask_used(um, mstride, s) && tt >= 0 && tt < NREL)
                              ? tt : NREL;
                myPk = s | (r << 24);
            }
            // issue ALL 16 gathers up front (idx always valid; dead edges
            // contribute via sel = 0)
            int   pk[16];
            f32x4 xv[16];
            #pragma unroll 16
            for (int e = 0; e < 16; ++e) {
                pk[e] = __shfl(myPk, lbase + e, 64);
                xv[e] = *(const f32x4*)(x + (long)(pk[e] & 0xFFFFFF) * NCH + l * 4);
            }
            #pragma unroll 16
            for (int e = 0; e < 16; ++e) {
                const int r = pk[e] >> 24;
                #pragma unroll
                for (int q = 0; q < NREL; ++q) {
                    const float sel = (r == q) ? 1.0f : 0.0f;
                    acc[q][0] += sel * xv[e].x;
                    acc[q][1] += sel * xv[e].y;
                    acc[q][2] += sel * xv[e].z;
                    acc[q][3] += sel * xv[e].w;
                }
            }
            for (int e = p0 + 16; e < p1; ++e) {   // general fallback (deg > 16)
                const int s = idx[e];
                const int tt = et[e];
                if (mask_used(um, mstride, s) && tt >= 0 && tt < NREL) {
                    const f32x4 w = *(const f32x4*)(x + (long)s * NCH + l * 4);
                    #pragma unroll
                    for (int q = 0; q < NREL; ++q) {
                        const float sel = (tt == q) ? 1.0f : 0.0f;
                        acc[q][0] += sel * w.x;
                        acc[q][1] += sel * w.y;
                        acc[q][2] += sel * w.z;
                        acc[q][3] += sel * w.w;
                    }
                }
            }
        }
        // bf16 pack -> swizzled LDS A[nd][k], k = q*128 + 4l + j
        #pragma unroll
        for (int q = 0; q < NREL; ++q) {
            ushort4 pkv;
            pkv.x = f2bf(acc[q][0]); pkv.y = f2bf(acc[q][1]);
            pkv.z = f2bf(acc[q][2]); pkv.w = f2bf(acc[q][3]);
            const int eb   = (q * NCH + l * 4) * 2;
            const int addr = (nd * 2048 + eb) ^ ((nd & 7) << 4);
            *(ushort4*)(As + addr) = pkv;
        }
    }
    __syncthreads();

    // phase 2: MFMA. wave wv covers output cols [wv*32, wv*32+32)
    const int wv   = t >> 6;
    const int lane = t & 63;
    const int row  = lane & 15;
    const int koff = (lane >> 4) * 8;
    const int col0 = wv * 32 + row;
    f32x4 c0 = {0.f, 0.f, 0.f, 0.f}, c1 = {0.f, 0.f, 0.f, 0.f};
    #pragma unroll 8
    for (int kt = 0; kt < 32; ++kt) {
        const int aaddr = (row * 2048 + (kt * 32 + koff) * 2) ^ ((row & 7) << 4);
        const bf16x8 a  = *(const bf16x8*)(As + aaddr);
        const bf16x8 b0 = *(const bf16x8*)(Wb + ((kt * NCH + col0) << 5) + koff);
        const bf16x8 b1 = *(const bf16x8*)(Wb + ((kt * NCH + col0 + 16) << 5) + koff);
        c0 = __builtin_amdgcn_mfma_f32_16x16x32_bf16(a, b0, c0, 0, 0, 0);
        c1 = __builtin_amdgcn_mfma_f32_16x16x32_bf16(a, b1, c1, 0, 0, 0);
    }
    const int r4 = (lane >> 4) * 4;
    #pragma unroll
    for (int j = 0; j < 4; ++j) {
        const int rr = r4 + j;
        const int n  = nid[rr];
        if (n >= 0) {
            const float sc = invdeg[rr];
            out[(long)n * NCH + col0]      = c0[j] * sc;
            out[(long)n * NCH + col0 + 16] = c1[j] * sc;
        }
    }
}

extern "C" void kernel_launch(void* const* d_in, const int* in_sizes, int n_in,
                              void* d_out, int out_size, void* d_ws, size_t ws_size,
                              hipStream_t stream) {
    const float*         x   = (const float*)d_in[0];
    const float*         W   = (const float*)d_in[1];
    const float*         hb  = (const float*)d_in[2];
    const int*           ptr = (const int*)d_in[3];
    const int*           idx = (const int*)d_in[4];
    const int*           et  = (const int*)d_in[5];
    const unsigned char* um  = (const unsigned char*)d_in[6];
    const int*           hm  = (const int*)d_in[7];
    const int*           hs  = (const int*)d_in[8];
    float* out = (float*)d_out;

    const int num_node = in_sizes[7];           // history_map length

    // ws layout: [0..7] int cn (count, mask stride), glist, Wb
    int* cn    = (int*)d_ws;
    int* glist = (int*)((char*)d_ws + 256);
    size_t wb_off = 256 + (((size_t)num_node * 4 + 255) / 256) * 256;
    unsigned short* Wb = (unsigned short*)((char*)d_ws + wb_off);

    hipMemsetAsync(cn, 0, 8, stream);           // zero compaction counter each call

    const int histBlocks = (num_node + 31) / 32;
    k_hist_prep<<<histBlocks + 16, 256, 0, stream>>>(
        hb, hm, hs, W, Wb, out, cn, glist, um, num_node, histBlocks);
    k_main<<<(num_node + 15) / 16, 256, 0, stream>>>(
        x, Wb, ptr, idx, et, um, cn, glist, out);
}